// Round 2
// baseline (190.431 us; speedup 1.0000x reference)
//
#include <hip/hip_runtime.h>

// Problem constants (fixed by the reference):
//   x:      (4, 3, 1024, 2048) fp32
//   weight: (3, 3, 3, 3)       fp32   w[o][c][p][q]
//   bn:     (1024, 2048)       int32
//   out:    (4, 3, 1024, 2048) fp32; active region [:, :, :1022, :1022]
//
// Structure exploited:
//   - gather column index is q in {0,1,2}: only x[:, :, :, 0:3] is ever read
//   - j1 = j % 256 -> pre-mask activation periodic in j with period 256
//   - bn in [-8, 0] so R = i+p+bn stays near i (negative wrap only for i<8)
//
// Two-kernel split:
//   A: compute v[b][o][i][jm] (12.6 MB) + float mask[i][j] (4 MB) into d_ws.
//      Gather-latency-bound but tiny (1022 blocks). Batch loop shares the
//      9 Rv index computations (4x fewer bn loads vs monolith).
//   B: pure streaming writer — aligned float4 loads from ws, float4 stores
//      to out. No LDS, no barrier, no gathers -> HBM-write-bound (~17 us).

#define HH 1024
#define WW 2048
#define HI 1022
#define WJ 1022

#define VWS_FLOATS (12 * 1024 * 256)   // v[b*3+o][i][jm]
// mask at ws + VWS_FLOATS: [1024][1024] floats (rows < 1022 valid)

__global__ __launch_bounds__(256) void compute_v_kernel(
    const float* __restrict__ x,
    const float* __restrict__ w,
    const int*   __restrict__ bn,
    float*       __restrict__ ws)
{
    const int i  = blockIdx.x;     // 0..1021
    const int jm = threadIdx.x;    // 0..255

    // ---- shared index computation (independent of b, c) ----
    int Rv[3][3];
    #pragma unroll
    for (int p = 0; p < 3; ++p) {
        const int r = i + p;                       // <= 1023
        const int* bnrow = bn + (size_t)r * WW;
        #pragma unroll
        for (int q = 0; q < 3; ++q) {
            int rv = r + bnrow[jm + q];            // jm+q <= 257
            if (rv < 0) rv += HH;                  // numpy negative-index wrap
            Rv[p][q] = rv;
        }
    }

    float acc[4][3];
    #pragma unroll
    for (int b = 0; b < 4; ++b)
        #pragma unroll
        for (int o = 0; o < 3; ++o)
            acc[b][o] = 0.f;

    #pragma unroll
    for (int b = 0; b < 4; ++b) {
        #pragma unroll
        for (int c = 0; c < 3; ++c) {
            const float* xbase = x + (size_t)(b * 3 + c) * (HH * WW);
            #pragma unroll
            for (int p = 0; p < 3; ++p) {
                #pragma unroll
                for (int q = 0; q < 3; ++q) {
                    const float xv = xbase[(size_t)Rv[p][q] * WW + q];
                    #pragma unroll
                    for (int o = 0; o < 3; ++o)
                        acc[b][o] += xv * w[(o * 3 + c) * 9 + p * 3 + q];
                }
            }
        }
    }

    #pragma unroll
    for (int b = 0; b < 4; ++b)
        #pragma unroll
        for (int o = 0; o < 3; ++o)
            ws[((size_t)(b * 3 + o) * HH + i) * 256 + jm] = acc[b][o];

    // ---- float mask row: mws[i][j] = (i+2 + bn[i+2][j+2] < H) && (j < 1022) ----
    float* mws = ws + VWS_FLOATS;
    const int* bnm = bn + (size_t)(i + 2) * WW;
    #pragma unroll
    for (int k = 0; k < 4; ++k) {
        const int j = jm + 256 * k;                // 0..1023
        float m = 0.f;
        if (j < WJ)
            m = ((i + 2) + bnm[j + 2] < HH) ? 1.f : 0.f;
        mws[(size_t)i * 1024 + j] = m;
    }
}

__global__ __launch_bounds__(256) void write_kernel(
    const float* __restrict__ ws,
    float*       __restrict__ out)
{
    const int bi = blockIdx.x;     // 0..4095
    const int b  = bi >> 10;
    const int i  = bi & 1023;
    const int j4 = threadIdx.x * 4;  // 0..1020

    const float4 z = make_float4(0.f, 0.f, 0.f, 0.f);

    if (i < HI) {
        const float* mrow = ws + VWS_FLOATS + (size_t)i * 1024;
        const float4 mm = *(const float4*)&mrow[j4];
        #pragma unroll
        for (int o = 0; o < 3; ++o) {
            const float* vrow = ws + ((size_t)(b * 3 + o) * HH + i) * 256;
            const float4 vv = *(const float4*)&vrow[j4 & 255];
            float* orow = out + ((size_t)(b * 3 + o) * HH + i) * WW;
            *(float4*)&orow[j4] = make_float4(vv.x * mm.x, vv.y * mm.y,
                                              vv.z * mm.z, vv.w * mm.w);
            *(float4*)&orow[j4 + 1024] = z;
        }
    } else {
        #pragma unroll
        for (int o = 0; o < 3; ++o) {
            float* orow = out + ((size_t)(b * 3 + o) * HH + i) * WW;
            *(float4*)&orow[j4]        = z;
            *(float4*)&orow[j4 + 1024] = z;
        }
    }
}

extern "C" void kernel_launch(void* const* d_in, const int* in_sizes, int n_in,
                              void* d_out, int out_size, void* d_ws, size_t ws_size,
                              hipStream_t stream) {
    const float* x   = (const float*)d_in[0];
    const float* w   = (const float*)d_in[1];
    const int*   bn  = (const int*)d_in[2];
    float*       out = (float*)d_out;
    float*       ws  = (float*)d_ws;   // needs 16 MB

    compute_v_kernel<<<dim3(HI), dim3(256), 0, stream>>>(x, w, bn, ws);
    write_kernel<<<dim3(4096), dim3(256), 0, stream>>>(ws, out);
}

// Round 3
// 183.388 us; speedup vs baseline: 1.0384x; 1.0384x over previous
//
#include <hip/hip_runtime.h>

// Problem constants (fixed by the reference):
//   x:      (4, 3, 1024, 2048) fp32
//   weight: (3, 3, 3, 3)       fp32   w[o][c][p][q]
//   bn:     (1024, 2048)       int32
//   out:    (4, 3, 1024, 2048) fp32; active region [:, :, :1022, :1022]
//
// Structure exploited:
//   - gather column index is q in {0,1,2}: only x[:, :, :, 0:3] is ever read
//   - j1 = j % 256 -> pre-mask activation periodic in j with period 256
//   - monolithic (R2's compute/write split de-overlapped gather latency and
//     regressed): one block per i handles ALL 4 batches, so the 9 bn loads,
//     Rv index math, and 4 mask loads are shared 4x vs the R1 per-(b,i) block.
//   - write stream (100.7 MB) is the roofline: ~16 us @ 6.7 TB/s.

#define HH 1024
#define WW 2048
#define HI 1022
#define WJ 1022

__global__ __launch_bounds__(256) void dis_conv_kernel(
    const float* __restrict__ x,
    const float* __restrict__ w,
    const int*   __restrict__ bn,
    float*       __restrict__ out)
{
    const int i = blockIdx.x;      // 0..1023
    const int t = threadIdx.x;     // 0..255

    __shared__ __align__(16) float v[12][256];    // v[b*3+o][jm]
    __shared__ __align__(16) float mask_s[1024];  // mask per j, 0 for j>=1022

    const bool activeRow = (i < HI);

    // ---- Phase 1: accumulate all 12 (b,o) activations for jm = t ----
    float acc[4][3];
    #pragma unroll
    for (int b = 0; b < 4; ++b)
        #pragma unroll
        for (int o = 0; o < 3; ++o)
            acc[b][o] = 0.f;

    if (activeRow) {
        // shared index computation (independent of b, c)
        int Rv[3][3];
        #pragma unroll
        for (int p = 0; p < 3; ++p) {
            const int* bnrow = bn + (size_t)(i + p) * WW;
            #pragma unroll
            for (int q = 0; q < 3; ++q) {
                int rv = i + p + bnrow[t + q];     // t+q <= 257
                if (rv < 0) rv += HH;              // numpy negative-index wrap
                Rv[p][q] = rv;
            }
        }
        #pragma unroll
        for (int b = 0; b < 4; ++b) {
            #pragma unroll
            for (int c = 0; c < 3; ++c) {
                const float* xbase = x + (size_t)(b * 3 + c) * (HH * WW);
                #pragma unroll
                for (int p = 0; p < 3; ++p) {
                    #pragma unroll
                    for (int q = 0; q < 3; ++q) {
                        const float xv = xbase[(size_t)Rv[p][q] * WW + q];
                        #pragma unroll
                        for (int o = 0; o < 3; ++o)
                            acc[b][o] += xv * w[(o * 3 + c) * 9 + p * 3 + q];
                    }
                }
            }
        }
    }
    #pragma unroll
    for (int b = 0; b < 4; ++b)
        #pragma unroll
        for (int o = 0; o < 3; ++o)
            v[b * 3 + o][t] = acc[b][o];

    // ---- mask row into LDS (zero-padded to 1024), shared by all 4 batches ----
    #pragma unroll
    for (int k = 0; k < 4; ++k) {
        const int j = t + 256 * k;                 // 0..1023
        float m = 0.f;
        if (activeRow && j < WJ)
            m = ((i + 2) + bn[(size_t)(i + 2) * WW + (j + 2)] < HH) ? 1.f : 0.f;
        mask_s[j] = m;
    }
    __syncthreads();

    // ---- Phase 2: stream 12 output rows (24 float4 stores / thread) ----
    const int j4 = t * 4;                          // 0..1020
    const float4 z = make_float4(0.f, 0.f, 0.f, 0.f);
    const float4 mm = *(const float4*)&mask_s[j4];
    #pragma unroll
    for (int bo = 0; bo < 12; ++bo) {
        float* orow = out + ((size_t)bo * HH + i) * WW;
        const float4 vv = *(const float4*)&v[bo][j4 & 255];
        *(float4*)&orow[j4] = make_float4(vv.x * mm.x, vv.y * mm.y,
                                          vv.z * mm.z, vv.w * mm.w);
        *(float4*)&orow[j4 + 1024] = z;
    }
}

extern "C" void kernel_launch(void* const* d_in, const int* in_sizes, int n_in,
                              void* d_out, int out_size, void* d_ws, size_t ws_size,
                              hipStream_t stream) {
    const float* x   = (const float*)d_in[0];
    const float* w   = (const float*)d_in[1];
    const int*   bn  = (const int*)d_in[2];
    float*       out = (float*)d_out;

    // one block per output row index i: 1024 blocks
    dis_conv_kernel<<<dim3(1024), dim3(256), 0, stream>>>(x, w, bn, out);
}

// Round 5
// 181.113 us; speedup vs baseline: 1.0514x; 1.0126x over previous
//
#include <hip/hip_runtime.h>

// Problem constants (fixed by the reference):
//   x:      (4, 3, 1024, 2048) fp32
//   weight: (3, 3, 3, 3)       fp32   w[o][c][p][q]
//   bn:     (1024, 2048)       int32
//   out:    (4, 3, 1024, 2048) fp32; active region [:, :, :1022, :1022]
//
// Structure exploited:
//   - gather column index is q in {0,1,2}: only x[:, :, :, 0:3] is ever read
//   - j1 = j % 256 -> pre-mask activation periodic in j with period 256
//   - one block per i handles ALL 4 batches (shared bn/Rv/mask work)
//   - nontemporal float4 stores (via ext_vector_type: the builtin rejects
//     HIP_vector_type): output (100.7 MB >> L2) should not write-allocate
//     in L2; match the fill kernel's streaming behavior.
//   - write stream (100.7 MB) is the roofline: ~16 us @ 6.6 TB/s.

#define HH 1024
#define WW 2048
#define HI 1022
#define WJ 1022

typedef float f32x4 __attribute__((ext_vector_type(4)));

__global__ __launch_bounds__(256) void dis_conv_kernel(
    const float* __restrict__ x,
    const float* __restrict__ w,
    const int*   __restrict__ bn,
    float*       __restrict__ out)
{
    const int i = blockIdx.x;      // 0..1023
    const int t = threadIdx.x;     // 0..255

    __shared__ __align__(16) float v[12][256];    // v[b*3+o][jm]
    __shared__ __align__(16) float mask_s[1024];  // mask per j, 0 for j>=1022

    const bool activeRow = (i < HI);

    // ---- Phase 1: accumulate all 12 (b,o) activations for jm = t ----
    float acc[4][3];
    #pragma unroll
    for (int b = 0; b < 4; ++b)
        #pragma unroll
        for (int o = 0; o < 3; ++o)
            acc[b][o] = 0.f;

    if (activeRow) {
        // shared index computation (independent of b, c)
        int Rv[3][3];
        #pragma unroll
        for (int p = 0; p < 3; ++p) {
            const int* bnrow = bn + (size_t)(i + p) * WW;
            #pragma unroll
            for (int q = 0; q < 3; ++q) {
                int rv = i + p + bnrow[t + q];     // t+q <= 257
                if (rv < 0) rv += HH;              // numpy negative-index wrap
                Rv[p][q] = rv;
            }
        }
        #pragma unroll
        for (int b = 0; b < 4; ++b) {
            #pragma unroll
            for (int c = 0; c < 3; ++c) {
                const float* xbase = x + (size_t)(b * 3 + c) * (HH * WW);
                #pragma unroll
                for (int p = 0; p < 3; ++p) {
                    #pragma unroll
                    for (int q = 0; q < 3; ++q) {
                        const float xv = xbase[(size_t)Rv[p][q] * WW + q];
                        #pragma unroll
                        for (int o = 0; o < 3; ++o)
                            acc[b][o] += xv * w[(o * 3 + c) * 9 + p * 3 + q];
                    }
                }
            }
        }
    }
    #pragma unroll
    for (int b = 0; b < 4; ++b)
        #pragma unroll
        for (int o = 0; o < 3; ++o)
            v[b * 3 + o][t] = acc[b][o];

    // ---- mask row into LDS (zero-padded to 1024), shared by all 4 batches ----
    #pragma unroll
    for (int k = 0; k < 4; ++k) {
        const int j = t + 256 * k;                 // 0..1023
        float m = 0.f;
        if (activeRow && j < WJ)
            m = ((i + 2) + bn[(size_t)(i + 2) * WW + (j + 2)] < HH) ? 1.f : 0.f;
        mask_s[j] = m;
    }
    __syncthreads();

    // ---- Phase 2: stream 12 output rows, nontemporal f32x4 stores ----
    const int j4 = t * 4;                          // 0..1020
    const f32x4 z = (f32x4)(0.f);
    const f32x4 mm = *(const f32x4*)&mask_s[j4];
    #pragma unroll
    for (int bo = 0; bo < 12; ++bo) {
        float* orow = out + ((size_t)bo * HH + i) * WW;
        const f32x4 vv = *(const f32x4*)&v[bo][j4 & 255];
        const f32x4 rv = vv * mm;
        __builtin_nontemporal_store(rv, (f32x4*)&orow[j4]);
        __builtin_nontemporal_store(z,  (f32x4*)&orow[j4 + 1024]);
    }
}

extern "C" void kernel_launch(void* const* d_in, const int* in_sizes, int n_in,
                              void* d_out, int out_size, void* d_ws, size_t ws_size,
                              hipStream_t stream) {
    const float* x   = (const float*)d_in[0];
    const float* w   = (const float*)d_in[1];
    const int*   bn  = (const int*)d_in[2];
    float*       out = (float*)d_out;

    // one block per output row index i: 1024 blocks
    dis_conv_kernel<<<dim3(1024), dim3(256), 0, stream>>>(x, w, bn, out);
}

// Round 6
// 176.650 us; speedup vs baseline: 1.0780x; 1.0253x over previous
//
#include <hip/hip_runtime.h>

// Problem constants (fixed by the reference):
//   x:      (4, 3, 1024, 2048) fp32
//   weight: (3, 3, 3, 3)       fp32   w[o][c][p][q]
//   bn:     (1024, 2048)       int32
//   out:    (4, 3, 1024, 2048) fp32; active region [:, :, :1022, :1022]
//
// Structure exploited:
//   - gather column index is q in {0,1,2}: only x[:, :, :, 0:3] is ever read
//   - j1 = j % 256 -> pre-mask activation periodic in j with period 256
//   - 4096 blocks, one per (b, i): R3/R5's 1024-block merged-batch variant
//     was ~4 us SLOWER once fill-speed noise is removed — more resident
//     blocks hide the scattered-gather latency behind other blocks' store
//     streams; the redundant per-batch bn/Rv work is latency-overlapped.
//   - nontemporal f32x4 stores: no L2 write-allocate churn on the 100.7 MB
//     output stream (output >> 32 MB L2).
//   - write stream (100.7 MB, re-poisoned every launch) is the roofline:
//     ~15-16 us @ 6.8 TB/s. Remaining dur_us is fixed harness traffic.

#define HH 1024
#define WW 2048
#define HI 1022
#define WJ 1022

typedef float f32x4 __attribute__((ext_vector_type(4)));

__global__ __launch_bounds__(256) void dis_conv_kernel(
    const float* __restrict__ x,
    const float* __restrict__ w,
    const int*   __restrict__ bn,
    float*       __restrict__ out)
{
    const int bi = blockIdx.x;      // 0..4095
    const int b  = bi >> 10;        // batch 0..3
    const int i  = bi & 1023;       // output row 0..1023
    const int t  = threadIdx.x;     // 0..255

    __shared__ __align__(16) float v[3][256];     // v[o][jm], jm = j % 256
    __shared__ __align__(16) float mask_s[1024];  // mask per j, 0 for j>=1022

    const bool activeRow = (i < HI);

    // ---- Phase 1: compute v[o][jm] for this row (jm = t) ----
    float acc0 = 0.f, acc1 = 0.f, acc2 = 0.f;
    if (activeRow) {
        int Rv[3][3];
        #pragma unroll
        for (int p = 0; p < 3; ++p) {
            const int* bnrow = bn + (size_t)(i + p) * WW;
            #pragma unroll
            for (int q = 0; q < 3; ++q) {
                int rv = i + p + bnrow[t + q];     // t+q <= 257
                if (rv < 0) rv += HH;              // numpy negative-index wrap
                Rv[p][q] = rv;
            }
        }
        #pragma unroll
        for (int c = 0; c < 3; ++c) {
            const float* xbase = x + (size_t)(b * 3 + c) * (HH * WW);
            #pragma unroll
            for (int p = 0; p < 3; ++p) {
                #pragma unroll
                for (int q = 0; q < 3; ++q) {
                    const float xv = xbase[(size_t)Rv[p][q] * WW + q];
                    acc0 += xv * w[(0 * 3 + c) * 9 + p * 3 + q];
                    acc1 += xv * w[(1 * 3 + c) * 9 + p * 3 + q];
                    acc2 += xv * w[(2 * 3 + c) * 9 + p * 3 + q];
                }
            }
        }
    }
    v[0][t] = acc0;
    v[1][t] = acc1;
    v[2][t] = acc2;

    // ---- mask row into LDS (zero-padded to 1024) ----
    #pragma unroll
    for (int k = 0; k < 4; ++k) {
        const int j = t + 256 * k;                 // 0..1023
        float m = 0.f;
        if (activeRow && j < WJ)
            m = ((i + 2) + bn[(size_t)(i + 2) * WW + (j + 2)] < HH) ? 1.f : 0.f;
        mask_s[j] = m;
    }
    __syncthreads();

    // ---- Phase 2: stream 3 output rows, nontemporal f32x4 stores ----
    const int j4 = t * 4;                          // 0..1020
    const f32x4 z = (f32x4)(0.f);
    const f32x4 mm = *(const f32x4*)&mask_s[j4];
    #pragma unroll
    for (int o = 0; o < 3; ++o) {
        float* orow = out + (((size_t)(b * 3 + o)) * HH + i) * WW;
        const f32x4 vv = *(const f32x4*)&v[o][j4 & 255];
        const f32x4 rv = vv * mm;
        __builtin_nontemporal_store(rv, (f32x4*)&orow[j4]);
        __builtin_nontemporal_store(z,  (f32x4*)&orow[j4 + 1024]);
    }
}

extern "C" void kernel_launch(void* const* d_in, const int* in_sizes, int n_in,
                              void* d_out, int out_size, void* d_ws, size_t ws_size,
                              hipStream_t stream) {
    const float* x   = (const float*)d_in[0];
    const float* w   = (const float*)d_in[1];
    const int*   bn  = (const int*)d_in[2];
    float*       out = (float*)d_out;

    // one block per (b, i) row: 4 * 1024 = 4096 blocks
    dis_conv_kernel<<<dim3(4096), dim3(256), 0, stream>>>(x, w, bn, out);
}